// Round 15
// baseline (373.813 us; speedup 1.0000x reference)
//
#include <hip/hip_runtime.h>
#include <stdint.h>

#define BB 8
#define NPT 8192
#define SPT 2048
#define C1D 128
#define C2D 256
#define CIN 384
#define HD 256
#define SPLIT 8
#define SC (SPT/SPLIT)   // 256 source points per chunk

typedef __attribute__((ext_vector_type(8))) short bf16x8;
typedef __attribute__((ext_vector_type(4))) float f32x4;

#define B2F(u) __uint_as_float(((unsigned int)(u)) << 16)

__device__ __forceinline__ unsigned short f2b(float f){
  unsigned int u = __float_as_uint(f);
  u += 0x7fffu + ((u >> 16) & 1u);   // RNE; inputs finite
  return (unsigned short)(u >> 16);
}

// ---------------- pack source points: gs[b*SPT+s] = (x,y,z,|c|^2), padding applied ----------------
// Must PRECEDE the main fused kernel (knn reads gs).
__global__ __launch_bounds__(256) void gsrc_kernel(const float* __restrict__ coor2,
    const unsigned char* __restrict__ pad, float4* __restrict__ gs){
  int i = blockIdx.x * 256 + threadIdx.x;      // i in [0, BB*SPT)
  int b = i >> 11, s = i & (SPT - 1);
  const float* cb = coor2 + b * 3 * SPT;
  float x = cb[s], y = cb[SPT + s], z = cb[2*SPT + s];
  if (pad[i]) { x = 1e19f; y = 1e19f; z = 1e19f; }
  float n2 = __fadd_rn(__fadd_rn(__fmul_rn(x,x), __fmul_rn(y,y)), __fmul_rn(z,z));
  gs[i] = make_float4(x, y, z, n2);
}

// ---------------- MAIN FUSED: knn_part (VALU-bound) || cvt + transposes (memory-bound) ------------
// R13 proven WIN (+14us): heterogeneous-block overlap — knn at 51% occupancy / ~0 HBM
// leaves memory pipes idle; the independent prep jobs backfill them in the SAME dispatch.
// knn blocks first. All branches block-uniform; knn FROZEN (R1/R4/R11 attacks all lost).
#define NB_KNN 2048                    // (NPT/256) * BB * SPLIT
#define NB_CVT 640                     // (HD*CIN + HD*HD)/256
#define NB_T2 4096                     // (SPT/32)*(C2D/32)*BB
#define NB_T1 8192                     // (NPT/32)*(C1D/32)*BB
__global__ __launch_bounds__(256) void main_kernel(
    const float* __restrict__ coor1, const float4* __restrict__ gs,
    float* __restrict__ cv, int* __restrict__ cj,
    const float* __restrict__ W1, const float* __restrict__ W2, unsigned short* __restrict__ Wb,
    const float* __restrict__ fea2, unsigned short* __restrict__ f2t,
    const float* __restrict__ fea1, unsigned short* __restrict__ xpm){
  __shared__ unsigned short t[32][33];
  int bid = blockIdx.x, tid = threadIdx.x;
  if (bid < NB_KNN){
    // ---- knn_part: 3-NN partial scan over one S-chunk (proven scalar version) ----
    // Distance math bit-exact vs numpy: dot=fl(fl(xx)+fl(yy))+fl(zz); d=fma(-2,dot,fl(n1+n2)).
    int x = bid & 31, b = (bid >> 5) & 7, c = bid >> 8;
    int s0c = c * SC;
    const float4* gsb = gs + b * SPT + s0c;
    int n = x * 256 + tid;
    const float* ca = coor1 + b * 3 * NPT;
    float x1 = ca[n], y1 = ca[NPT + n], z1 = ca[2*NPT + n];
    float n1 = __fadd_rn(__fadd_rn(__fmul_rn(x1,x1), __fmul_rn(y1,y1)), __fmul_rn(z1,z1));
    float v0 = 3.4e38f, v1 = 3.4e38f, v2 = 3.4e38f;
    int j0 = 0, j1 = 0, j2 = 0;
    #pragma unroll 8
    for (int s = 0; s < SC; s++){
      float4 q = gsb[s];                       // uniform address -> SGPR load
      float dot = __fadd_rn(__fadd_rn(__fmul_rn(x1,q.x), __fmul_rn(y1,q.y)), __fmul_rn(z1,q.z));
      float npn = __fadd_rn(n1, q.w);
      float d = __builtin_fmaf(-2.0f, dot, npn);
      bool l0 = d < v0, l1 = d < v1, l2 = d < v2;  // strict < keeps earliest index on ties
      j2 = l1 ? j1 : (l2 ? s : j2);
      j1 = l0 ? j0 : (l1 ? s : j1);
      j0 = l0 ? s  : j0;
      float nv2 = __builtin_amdgcn_fmed3f(v1, v2, d);
      float nv1 = __builtin_amdgcn_fmed3f(v0, v1, d);
      v0 = fminf(v0, d); v1 = nv1; v2 = nv2;
    }
    size_t m = (size_t)b * NPT + n;
    size_t base = (m * SPLIT + c) * 3;
    cv[base+0] = v0; cv[base+1] = v1; cv[base+2] = v2;
    cj[base+0] = s0c + j0; cj[base+1] = s0c + j1; cj[base+2] = s0c + j2;
    return;
  }
  bid -= NB_KNN;
  if (bid < NB_CVT){
    int i = bid * 256 + tid;
    const int n1 = HD * CIN;
    if (i < n1) Wb[i] = f2b(W1[i]);
    else { int k = i - n1; if (k < HD * HD) Wb[n1 + k] = f2b(W2[k]); }
    return;
  }
  bid -= NB_CVT;
  // transpose job: [B,C,N] f32 -> [B,N,C(dstStride)] bf16
  const float* src; unsigned short* dst; int Cdim, Ndim, dstStride, n0, c0, b;
  if (bid < NB_T2){
    src = fea2; dst = f2t; Cdim = C2D; Ndim = SPT; dstStride = C2D;
    n0 = (bid & 63) * 32; c0 = ((bid >> 6) & 7) * 32; b = bid >> 9;
  } else {
    bid -= NB_T2;
    src = fea1; dst = xpm; Cdim = C1D; Ndim = NPT; dstStride = CIN;
    n0 = (bid & 255) * 32; c0 = ((bid >> 8) & 3) * 32; b = bid >> 10;
  }
  int tx = tid & 31, ty = tid >> 5;
  const float* s = src + (size_t)b * Cdim * Ndim;
  unsigned short* d = dst + (size_t)b * Ndim * dstStride;
  #pragma unroll
  for (int i = 0; i < 4; i++)
    t[ty + i*8][tx] = f2b(s[(size_t)(c0 + ty + i*8) * Ndim + n0 + tx]);
  __syncthreads();
  #pragma unroll
  for (int i = 0; i < 4; i++)
    d[(size_t)(n0 + ty + i*8) * dstStride + c0 + tx] = t[tx][ty + i*8];
}

// ---------------- WAVE-AUTONOMOUS FUSED MLP: merge+interp+GEMM1+LN+GEMM2+LN, ZERO barriers -------
// R14 analysis: 20 K-chunks x 2 block-barriers dominated (MfmaUtil 11% at 72us; ~2000cyc/chunk
// vs ~180cyc work). Every producer->consumer edge is wave-local EXCEPT the shared Ws tile:
//  - stage A: lane L<16 of wave w merges point w*16+L (results stay in regs, shfl'd out)
//  - stage B: wave w gathers/blends X' rows w*16..+15 into its own Hbuf rows
//  - phase 1/2: bfrag rows ml=w*16+col (own rows); H-write same rows; LN = intra-wave shfl
// So: drop W staging entirely — read A-fragments STRAIGHT FROM GLOBAL (byte-identical values;
// W1b+W2b = 327KB L2-resident; 16KB chunk working set hits L1 for quad/wave redundancy).
// Result: NO __syncthreads/bar_sync at all; LDS = Hbuf only (33792B) -> 4 blocks/CU, 16 waves.
// Same arithmetic & operand bytes as R14 => bit-exact.
__global__ __launch_bounds__(256) void mlp_fused_kernel(
    const float* __restrict__ cv, const int* __restrict__ cj,
    const unsigned short* __restrict__ f2t, const unsigned short* __restrict__ xpm,
    const unsigned short* __restrict__ W1g, const unsigned short* __restrict__ W2g,
    const float* __restrict__ b1, const float* __restrict__ g1, const float* __restrict__ be1,
    const float* __restrict__ b2, const float* __restrict__ g2, const float* __restrict__ be2,
    float* __restrict__ outg){
  __shared__ __align__(16) unsigned short Hbuf[64*264];   // X' ch128..383, then H; rows wave-private
  int tid = threadIdx.x;
  int m0 = blockIdx.x * 64;
  int b = m0 >> 13, n0 = m0 & (NPT - 1);
  int w = tid >> 6, lane = tid & 63, col = lane & 15, quad = lane >> 4;
  int ml = w*16 + col;                                    // this lane's point row (0..63)

  // ---- stage A (wave-local): lane<16 merges SPLIT x top-3 for point m0+w*16+lane ----
  // chunk-ascending insert order + strict < == global sequential scan tie-order
  float w0r = 0.f, w1r = 0.f, w2r = 0.f;
  int j0r = 0, j1r = 0, j2r = 0;
  if (lane < 16){
    size_t m = (size_t)m0 + w*16 + lane;
    float v0 = 3.4e38f, v1 = 3.4e38f, v2 = 3.4e38f;
    int j0 = 0, j1 = 0, j2 = 0;
    #pragma unroll
    for (int c = 0; c < SPLIT; c++){
      #pragma unroll
      for (int k = 0; k < 3; k++){
        float d = cv[(m * SPLIT + c) * 3 + k];
        int j   = cj[(m * SPLIT + c) * 3 + k];
        bool l0 = d < v0, l1 = d < v1, l2 = d < v2;
        j2 = l1 ? j1 : (l2 ? j : j2);
        j1 = l0 ? j0 : (l1 ? j : j1);
        j0 = l0 ? j  : j0;
        float nv2 = __builtin_amdgcn_fmed3f(v1, v2, d);
        float nv1 = __builtin_amdgcn_fmed3f(v0, v1, d);
        v0 = fminf(v0, d); v1 = nv1; v2 = nv2;
      }
    }
    float r0 = 1.0f / fmaxf(v0, 1e-8f);
    float r1 = 1.0f / fmaxf(v1, 1e-8f);
    float r2 = 1.0f / fmaxf(v2, 1e-8f);
    float rs = (r0 + r1) + r2;
    w0r = r0 / rs; w1r = r1 / rs; w2r = r2 / rs;
    j0r = j0; j1r = j1; j2r = j2;
  }

  // ---- stage B (wave-local): interp -> X' rows w*16..+15 (weights/indices via shfl) ----
  #pragma unroll 4
  for (int i = 0; i < 16; i++){
    float w0 = __shfl(w0r, i), w1 = __shfl(w1r, i), w2 = __shfl(w2r, i);
    int j0 = __shfl(j0r, i), j1 = __shfl(j1r, i), j2 = __shfl(j2r, i);
    const ushort4 a  = *(const ushort4*)(f2t + (size_t)(b*SPT + j0) * C2D + lane*4);
    const ushort4 c4 = *(const ushort4*)(f2t + (size_t)(b*SPT + j1) * C2D + lane*4);
    const ushort4 e  = *(const ushort4*)(f2t + (size_t)(b*SPT + j2) * C2D + lane*4);
    ushort4 o;
    o.x = f2b(w0*B2F(a.x) + w1*B2F(c4.x) + w2*B2F(e.x));
    o.y = f2b(w0*B2F(a.y) + w1*B2F(c4.y) + w2*B2F(e.y));
    o.z = f2b(w0*B2F(a.z) + w1*B2F(c4.z) + w2*B2F(e.z));
    o.w = f2b(w0*B2F(a.w) + w1*B2F(c4.w) + w2*B2F(e.w));
    *(ushort4*)(Hbuf + (w*16 + i)*264 + lane*4) = o;   // X'[p][ch-128]
  }

  f32x4 acc[16];
  #pragma unroll
  for (int i = 0; i < 16; i++) acc[i] = (f32x4)0.0f;

  // ---------------- phase 1: H = relu(LN1(W1 @ x + b1)) — no barriers, W from global ----------
  const unsigned short* xrow = xpm + (size_t)(m0 + ml) * CIN + quad*8;
  for (int c = 0; c < 12; c++){
    bf16x8 bfrag = (c < 4)
      ? *(const bf16x8*)(xrow + c*32)                          // fea1 ch 0..127 (global, own row)
      : *(const bf16x8*)(Hbuf + ml*264 + (c-4)*32 + quad*8);   // X' ch 128..383 (LDS, own row)
    #pragma unroll
    for (int ot = 0; ot < 16; ot++){
      bf16x8 afrag = *(const bf16x8*)(W1g + (size_t)(ot*16 + col) * CIN + c*32 + quad*8);
      acc[ot] = __builtin_amdgcn_mfma_f32_16x16x32_bf16(afrag, bfrag, acc[ot], 0, 0, 0);
    }
  }
  {
    const float4* b1v = (const float4*)b1;
    const float4* g1v = (const float4*)g1;
    const float4* be1v = (const float4*)be1;
    float s1 = 0.f, s2 = 0.f;
    #pragma unroll
    for (int ot = 0; ot < 16; ot++){
      float4 bb = b1v[ot*4 + quad];     // b1[ot*16+quad*4 .. +3], identical f32 values
      float v0a = acc[ot][0] + bb.x, v1a = acc[ot][1] + bb.y;
      float v2a = acc[ot][2] + bb.z, v3a = acc[ot][3] + bb.w;
      acc[ot][0] = v0a; acc[ot][1] = v1a; acc[ot][2] = v2a; acc[ot][3] = v3a;
      s1 += v0a; s2 += v0a*v0a; s1 += v1a; s2 += v1a*v1a;
      s1 += v2a; s2 += v2a*v2a; s1 += v3a; s2 += v3a*v3a;
    }
    s1 += __shfl_xor(s1, 16); s1 += __shfl_xor(s1, 32);
    s2 += __shfl_xor(s2, 16); s2 += __shfl_xor(s2, 32);
    float mu = s1 * (1.f/256.f);
    float rinv = rsqrtf(s2 * (1.f/256.f) - mu*mu + 1e-5f);
    // H overwrites this wave's OWN Hbuf rows; this wave's X' reads are already consumed
    // (in-order lgkm within wave). No cross-wave access to these rows anywhere.
    #pragma unroll
    for (int ot = 0; ot < 16; ot++){
      float4 gg = g1v[ot*4 + quad];
      float4 ee = be1v[ot*4 + quad];
      ushort4 hv;
      hv.x = f2b(fmaxf((acc[ot][0] - mu) * rinv * gg.x + ee.x, 0.f));
      hv.y = f2b(fmaxf((acc[ot][1] - mu) * rinv * gg.y + ee.y, 0.f));
      hv.z = f2b(fmaxf((acc[ot][2] - mu) * rinv * gg.z + ee.z, 0.f));
      hv.w = f2b(fmaxf((acc[ot][3] - mu) * rinv * gg.w + ee.w, 0.f));
      *(ushort4*)(Hbuf + ml*264 + ot*16 + quad*4) = hv;
    }
  }

  // ---------------- phase 2: out = relu(LN2(W2 @ H + b2)) — no barriers, W from global ---------
  #pragma unroll
  for (int i = 0; i < 16; i++) acc[i] = (f32x4)0.0f;
  for (int c = 0; c < 8; c++){
    bf16x8 bfrag = *(const bf16x8*)(Hbuf + ml*264 + c*32 + quad*8);   // own row
    #pragma unroll
    for (int ot = 0; ot < 16; ot++){
      bf16x8 afrag = *(const bf16x8*)(W2g + (size_t)(ot*16 + col) * HD + c*32 + quad*8);
      acc[ot] = __builtin_amdgcn_mfma_f32_16x16x32_bf16(afrag, bfrag, acc[ot], 0, 0, 0);
    }
  }
  {
    const float4* b2v = (const float4*)b2;
    const float4* g2v = (const float4*)g2;
    const float4* be2v = (const float4*)be2;
    float s1 = 0.f, s2 = 0.f;
    #pragma unroll
    for (int ot = 0; ot < 16; ot++){
      float4 bb = b2v[ot*4 + quad];
      float v0a = acc[ot][0] + bb.x, v1a = acc[ot][1] + bb.y;
      float v2a = acc[ot][2] + bb.z, v3a = acc[ot][3] + bb.w;
      acc[ot][0] = v0a; acc[ot][1] = v1a; acc[ot][2] = v2a; acc[ot][3] = v3a;
      s1 += v0a; s2 += v0a*v0a; s1 += v1a; s2 += v1a*v1a;
      s1 += v2a; s2 += v2a*v2a; s1 += v3a; s2 += v3a*v3a;
    }
    s1 += __shfl_xor(s1, 16); s1 += __shfl_xor(s1, 32);
    s2 += __shfl_xor(s2, 16); s2 += __shfl_xor(s2, 32);
    float mu = s1 * (1.f/256.f);
    float rinv = rsqrtf(s2 * (1.f/256.f) - mu*mu + 1e-5f);
    size_t obase = (size_t)b * HD * NPT + n0 + w*16 + col;
    #pragma unroll
    for (int ot = 0; ot < 16; ot++){
      float4 gg = g2v[ot*4 + quad];
      float4 ee = be2v[ot*4 + quad];
      float o0 = fmaxf((acc[ot][0] - mu) * rinv * gg.x + ee.x, 0.f);
      float o1 = fmaxf((acc[ot][1] - mu) * rinv * gg.y + ee.y, 0.f);
      float o2 = fmaxf((acc[ot][2] - mu) * rinv * gg.z + ee.z, 0.f);
      float o3 = fmaxf((acc[ot][3] - mu) * rinv * gg.w + ee.w, 0.f);
      int ob = ot*16 + quad*4;
      outg[obase + (size_t)(ob+0) * NPT] = o0;
      outg[obase + (size_t)(ob+1) * NPT] = o1;
      outg[obase + (size_t)(ob+2) * NPT] = o2;
      outg[obase + (size_t)(ob+3) * NPT] = o3;
    }
  }
}

extern "C" void kernel_launch(void* const* d_in, const int* in_sizes, int n_in,
                              void* d_out, int out_size, void* d_ws, size_t ws_size,
                              hipStream_t stream){
  const float* coor1 = (const float*)d_in[0];
  const float* coor2 = (const float*)d_in[1];
  const float* fea1  = (const float*)d_in[2];
  const float* fea2  = (const float*)d_in[3];
  const unsigned char* pad = (const unsigned char*)d_in[4];
  const float* W1  = (const float*)d_in[5];
  const float* b1  = (const float*)d_in[6];
  const float* g1  = (const float*)d_in[7];
  const float* be1 = (const float*)d_in[8];
  const float* W2  = (const float*)d_in[9];
  const float* b2  = (const float*)d_in[10];
  const float* g2  = (const float*)d_in[11];
  const float* be2 = (const float*)d_in[12];
  float* out = (float*)d_out;

  // ws layout (~94.2 MB, proven footprint): | W1b | W2b | f2t | xpm | scratch
  // cv/cj/gs alias the old Hg region (knn-stage scratch only)
  char* ws = (char*)d_ws;
  unsigned short* W1b  = (unsigned short*)(ws + 1573120);
  unsigned short* W2b  = (unsigned short*)(ws + 1769728);
  unsigned short* f2t  = (unsigned short*)(ws + 1900800);
  unsigned short* xpm  = (unsigned short*)(ws + 10289408);
  float* cv            = (float*)(ws + 60621056);             // knn scratch
  int*   cj            = (int*)  (ws + 60621056 + 6291456);
  float4* gs           = (float4*)(ws + 60621056 + 16777216);

  gsrc_kernel<<<BB*SPT/256, 256, 0, stream>>>(coor2, pad, gs);
  main_kernel<<<NB_KNN + NB_CVT + NB_T2 + NB_T1, 256, 0, stream>>>(
      coor1, gs, cv, cj, W1, W2, W1b, fea2, f2t, fea1, xpm);
  mlp_fused_kernel<<<BB*NPT/64, 256, 0, stream>>>(
      cv, cj, f2t, xpm, W1b, W2b, b1, g1, be1, b2, g2, be2, out);
}

// Round 16
// 300.825 us; speedup vs baseline: 1.2426x; 1.2426x over previous
//
#include <hip/hip_runtime.h>
#include <stdint.h>

#define BB 8
#define NPT 8192
#define SPT 2048
#define C1D 128
#define C2D 256
#define CIN 384
#define HD 256
#define SPLIT 8
#define SC (SPT/SPLIT)   // 256 source points per chunk

typedef __attribute__((ext_vector_type(8))) short bf16x8;
typedef __attribute__((ext_vector_type(4))) float f32x4;

#define B2F(u) __uint_as_float(((unsigned int)(u)) << 16)

__device__ __forceinline__ unsigned short f2b(float f){
  unsigned int u = __float_as_uint(f);
  u += 0x7fffu + ((u >> 16) & 1u);   // RNE; inputs finite
  return (unsigned short)(u >> 16);
}

// Workgroup barrier that does NOT drain vmcnt (prefetched global loads stay in
// flight) but IS safe against the rule-18 compiler trap: register-only MFMA is
// not ordered by an asm "memory" clobber, so without sched_barrier(0) the
// scheduler can sink MFMAs (and their covering lgkmcnt waits) past s_barrier.
// sched_barrier(0) pins ALL instructions; lgkmcnt(0) covers LDS ops. vmcnt
// untouched — the whole point vs __syncthreads (R7: 66->83us regression).
__device__ __forceinline__ void bar_sync(){
  __builtin_amdgcn_sched_barrier(0);
  asm volatile("s_waitcnt lgkmcnt(0)" ::: "memory");
  __builtin_amdgcn_s_barrier();
  __builtin_amdgcn_sched_barrier(0);
}

// ---------------- pack source points: gs[b*SPT+s] = (x,y,z,|c|^2), padding applied ----------------
__global__ __launch_bounds__(256) void gsrc_kernel(const float* __restrict__ coor2,
    const unsigned char* __restrict__ pad, float4* __restrict__ gs){
  int i = blockIdx.x * 256 + threadIdx.x;      // i in [0, BB*SPT)
  int b = i >> 11, s = i & (SPT - 1);
  const float* cb = coor2 + b * 3 * SPT;
  float x = cb[s], y = cb[SPT + s], z = cb[2*SPT + s];
  if (pad[i]) { x = 1e19f; y = 1e19f; z = 1e19f; }
  float n2 = __fadd_rn(__fadd_rn(__fmul_rn(x,x), __fmul_rn(y,y)), __fmul_rn(z,z));
  gs[i] = make_float4(x, y, z, n2);
}

// ---------------- MAIN FUSED: knn_part (VALU-bound) || cvt + transposes (memory-bound) ------------
// R13 proven WIN (+14us): heterogeneous-block overlap. knn FROZEN (R1/R4/R11 attacks lost).
#define NB_KNN 2048                    // (NPT/256) * BB * SPLIT
#define NB_CVT 640                     // (HD*CIN + HD*HD)/256
#define NB_T2 4096                     // (SPT/32)*(C2D/32)*BB
#define NB_T1 8192                     // (NPT/32)*(C1D/32)*BB
__global__ __launch_bounds__(256) void main_kernel(
    const float* __restrict__ coor1, const float4* __restrict__ gs,
    float* __restrict__ cv, int* __restrict__ cj,
    const float* __restrict__ W1, const float* __restrict__ W2, unsigned short* __restrict__ Wb,
    const float* __restrict__ fea2, unsigned short* __restrict__ f2t,
    const float* __restrict__ fea1, unsigned short* __restrict__ xpm){
  __shared__ unsigned short t[32][33];
  int bid = blockIdx.x, tid = threadIdx.x;
  if (bid < NB_KNN){
    // ---- knn_part: bit-exact distance: dot=fl(fl(xx)+fl(yy))+fl(zz); d=fma(-2,dot,fl(n1+n2)).
    int x = bid & 31, b = (bid >> 5) & 7, c = bid >> 8;
    int s0c = c * SC;
    const float4* gsb = gs + b * SPT + s0c;
    int n = x * 256 + tid;
    const float* ca = coor1 + b * 3 * NPT;
    float x1 = ca[n], y1 = ca[NPT + n], z1 = ca[2*NPT + n];
    float n1 = __fadd_rn(__fadd_rn(__fmul_rn(x1,x1), __fmul_rn(y1,y1)), __fmul_rn(z1,z1));
    float v0 = 3.4e38f, v1 = 3.4e38f, v2 = 3.4e38f;
    int j0 = 0, j1 = 0, j2 = 0;
    #pragma unroll 8
    for (int s = 0; s < SC; s++){
      float4 q = gsb[s];                       // uniform address -> SGPR load
      float dot = __fadd_rn(__fadd_rn(__fmul_rn(x1,q.x), __fmul_rn(y1,q.y)), __fmul_rn(z1,q.z));
      float npn = __fadd_rn(n1, q.w);
      float d = __builtin_fmaf(-2.0f, dot, npn);
      bool l0 = d < v0, l1 = d < v1, l2 = d < v2;  // strict < keeps earliest index on ties
      j2 = l1 ? j1 : (l2 ? s : j2);
      j1 = l0 ? j0 : (l1 ? s : j1);
      j0 = l0 ? s  : j0;
      float nv2 = __builtin_amdgcn_fmed3f(v1, v2, d);
      float nv1 = __builtin_amdgcn_fmed3f(v0, v1, d);
      v0 = fminf(v0, d); v1 = nv1; v2 = nv2;
    }
    size_t m = (size_t)b * NPT + n;
    size_t base = (m * SPLIT + c) * 3;
    cv[base+0] = v0; cv[base+1] = v1; cv[base+2] = v2;
    cj[base+0] = s0c + j0; cj[base+1] = s0c + j1; cj[base+2] = s0c + j2;
    return;
  }
  bid -= NB_KNN;
  if (bid < NB_CVT){
    int i = bid * 256 + tid;
    const int n1 = HD * CIN;
    if (i < n1) Wb[i] = f2b(W1[i]);
    else { int k = i - n1; if (k < HD * HD) Wb[n1 + k] = f2b(W2[k]); }
    return;
  }
  bid -= NB_CVT;
  // transpose job: [B,C,N] f32 -> [B,N,C(dstStride)] bf16
  const float* src; unsigned short* dst; int Cdim, Ndim, dstStride, n0, c0, b;
  if (bid < NB_T2){
    src = fea2; dst = f2t; Cdim = C2D; Ndim = SPT; dstStride = C2D;
    n0 = (bid & 63) * 32; c0 = ((bid >> 6) & 7) * 32; b = bid >> 9;
  } else {
    bid -= NB_T2;
    src = fea1; dst = xpm; Cdim = C1D; Ndim = NPT; dstStride = CIN;
    n0 = (bid & 255) * 32; c0 = ((bid >> 8) & 3) * 32; b = bid >> 10;
  }
  int tx = tid & 31, ty = tid >> 5;
  const float* s = src + (size_t)b * Cdim * Ndim;
  unsigned short* d = dst + (size_t)b * Ndim * dstStride;
  #pragma unroll
  for (int i = 0; i < 4; i++)
    t[ty + i*8][tx] = f2b(s[(size_t)(c0 + ty + i*8) * Ndim + n0 + tx]);
  __syncthreads();
  #pragma unroll
  for (int i = 0; i < 4; i++)
    d[(size_t)(n0 + ty + i*8) * dstStride + c0 + tx] = t[tx][ty + i*8];
}

// ---------------- FUSED MLP v3: R14 skeleton + K-chunk 64 (half the barriers) ----------------
// R15 lesson: Ws-in-LDS is load-bearing (global W reads = VMEM-bound 3x regression);
// the barriers protect block-level W reuse. So keep them but AMORTIZE: K=64 chunks ->
// 10 barrier-pairs instead of 20, 32 MFMA per pair instead of 16.
// LDS budget funded by R15-PROVEN pieces: stage A/B wave-local via shfl (no sW3/sI3);
// phase-1 ch0..127 bfrags per-lane own-row from global xpm (prefetched, no Xs);
// Hbuf rows wave-private (no barrier around X'-read/H-write/H-read).
// LDS: Ws[256][72] 36864 + Hbuf[64][264] 33792 + params 3072 = 73728 -> 2 blocks/CU.
// Params stay in LDS (R10: pulling them to regs blew VGPR 120->176).
__global__ __launch_bounds__(256) void mlp_fused_kernel(
    const float* __restrict__ cv, const int* __restrict__ cj,
    const unsigned short* __restrict__ f2t, const unsigned short* __restrict__ xpm,
    const unsigned short* __restrict__ W1g, const unsigned short* __restrict__ W2g,
    const float* __restrict__ b1, const float* __restrict__ g1, const float* __restrict__ be1,
    const float* __restrict__ b2, const float* __restrict__ g2, const float* __restrict__ be2,
    float* __restrict__ outg){
  __shared__ __align__(16) unsigned short Ws[256*72];     // W chunk [256 o][64 k] pad->72
  __shared__ __align__(16) unsigned short Hbuf[64*264];   // X' ch128..383, then H; rows wave-private
  __shared__ float sB[256], sG[256], sBe[256];
  int tid = threadIdx.x;
  int m0 = blockIdx.x * 64;
  int b = m0 >> 13, n0 = m0 & (NPT - 1);
  int w = tid >> 6, lane = tid & 63, col = lane & 15, quad = lane >> 4;
  int ml = w*16 + col;                                    // this lane's point row (0..63)
  const int4* wsrc = (const int4*)(W1g + (size_t)tid * CIN);   // 8 int4 per 64-k chunk
  // prefetch: W1 chunk 0 (8 int4) + own-row X ch0..127 (4 bf16x8) — in flight under stages A/B
  int4 wA[8];
  #pragma unroll
  for (int i = 0; i < 8; i++) wA[i] = wsrc[i];
  const unsigned short* xrow = xpm + (size_t)(m0 + ml) * CIN + quad*8;
  bf16x8 xA[4];
  #pragma unroll
  for (int i = 0; i < 4; i++) xA[i] = *(const bf16x8*)(xrow + i*32);
  sB[tid] = b1[tid]; sG[tid] = g1[tid]; sBe[tid] = be1[tid];

  // ---- stage A (wave-local, R15-proven): lane<16 merges SPLIT x top-3 for point m0+w*16+lane --
  float w0r = 0.f, w1r = 0.f, w2r = 0.f;
  int j0r = 0, j1r = 0, j2r = 0;
  if (lane < 16){
    size_t m = (size_t)m0 + w*16 + lane;
    float v0 = 3.4e38f, v1 = 3.4e38f, v2 = 3.4e38f;
    int j0 = 0, j1 = 0, j2 = 0;
    #pragma unroll
    for (int c = 0; c < SPLIT; c++){
      #pragma unroll
      for (int k = 0; k < 3; k++){
        float d = cv[(m * SPLIT + c) * 3 + k];
        int j   = cj[(m * SPLIT + c) * 3 + k];
        bool l0 = d < v0, l1 = d < v1, l2 = d < v2;
        j2 = l1 ? j1 : (l2 ? j : j2);
        j1 = l0 ? j0 : (l1 ? j : j1);
        j0 = l0 ? j  : j0;
        float nv2 = __builtin_amdgcn_fmed3f(v1, v2, d);
        float nv1 = __builtin_amdgcn_fmed3f(v0, v1, d);
        v0 = fminf(v0, d); v1 = nv1; v2 = nv2;
      }
    }
    float r0 = 1.0f / fmaxf(v0, 1e-8f);
    float r1 = 1.0f / fmaxf(v1, 1e-8f);
    float r2 = 1.0f / fmaxf(v2, 1e-8f);
    float rs = (r0 + r1) + r2;
    w0r = r0 / rs; w1r = r1 / rs; w2r = r2 / rs;
    j0r = j0; j1r = j1; j2r = j2;
  }

  // ---- stage B (wave-local, R15-proven): interp -> X' own rows (weights/indices via shfl) ----
  #pragma unroll 4
  for (int i = 0; i < 16; i++){
    float w0 = __shfl(w0r, i), w1 = __shfl(w1r, i), w2 = __shfl(w2r, i);
    int j0 = __shfl(j0r, i), j1 = __shfl(j1r, i), j2 = __shfl(j2r, i);
    const ushort4 a  = *(const ushort4*)(f2t + (size_t)(b*SPT + j0) * C2D + lane*4);
    const ushort4 c4 = *(const ushort4*)(f2t + (size_t)(b*SPT + j1) * C2D + lane*4);
    const ushort4 e  = *(const ushort4*)(f2t + (size_t)(b*SPT + j2) * C2D + lane*4);
    ushort4 o;
    o.x = f2b(w0*B2F(a.x) + w1*B2F(c4.x) + w2*B2F(e.x));
    o.y = f2b(w0*B2F(a.y) + w1*B2F(c4.y) + w2*B2F(e.y));
    o.z = f2b(w0*B2F(a.z) + w1*B2F(c4.z) + w2*B2F(e.z));
    o.w = f2b(w0*B2F(a.w) + w1*B2F(c4.w) + w2*B2F(e.w));
    *(ushort4*)(Hbuf + (w*16 + i)*264 + lane*4) = o;   // X'[p][ch-128]
  }

  f32x4 acc[16];
  #pragma unroll
  for (int i = 0; i < 16; i++) acc[i] = (f32x4)0.0f;

  // ---------------- phase 1: H = relu(LN1(W1 @ x + b1)) — 6 chunks of K=64 ----------------
  for (int c = 0; c < 6; c++){
    bar_sync();                         // previous chunk's Ws readers drained (vmcnt untouched)
    {
      int4* d4 = (int4*)(Ws + tid * 72);
      #pragma unroll
      for (int i = 0; i < 8; i++) d4[i] = wA[i];
    }
    if (c + 1 < 6){                     // issue next chunk's loads NOW; they stay in flight
      #pragma unroll
      for (int i = 0; i < 8; i++) wA[i] = wsrc[(c+1)*8 + i];
    }
    bar_sync();                         // staged writes visible; prefetch still in flight
    #pragma unroll
    for (int ks = 0; ks < 2; ks++){
      int kc = c*2 + ks;                // 32-k subchunk 0..11 (compile-time after unroll)
      bf16x8 bfrag = (kc < 4)
        ? xA[kc]                                              // ch 0..127 (prefetched, own row)
        : *(const bf16x8*)(Hbuf + ml*264 + (kc-4)*32 + quad*8); // X' ch 128..383 (own row)
      #pragma unroll
      for (int ot = 0; ot < 16; ot++){
        bf16x8 afrag = *(const bf16x8*)(Ws + (ot*16 + col)*72 + ks*32 + quad*8);
        acc[ot] = __builtin_amdgcn_mfma_f32_16x16x32_bf16(afrag, bfrag, acc[ot], 0, 0, 0);
      }
    }
  }
  // issue phase-2 prologue loads early: W2 chunk 0 + layer-2 params
  const int4* w2src = (const int4*)(W2g + (size_t)tid * HD);
  int4 wB[8];
  #pragma unroll
  for (int i = 0; i < 8; i++) wB[i] = w2src[i];
  float rb2 = b2[tid], rg2 = g2[tid], rbe2 = be2[tid];
  {
    float s1 = 0.f, s2 = 0.f;
    #pragma unroll
    for (int ot = 0; ot < 16; ot++)
      #pragma unroll
      for (int r = 0; r < 4; r++){
        int o = ot*16 + quad*4 + r;
        float v = acc[ot][r] + sB[o];
        acc[ot][r] = v;
        s1 += v; s2 += v*v;
      }
    s1 += __shfl_xor(s1, 16); s1 += __shfl_xor(s1, 32);
    s2 += __shfl_xor(s2, 16); s2 += __shfl_xor(s2, 32);
    float mu = s1 * (1.f/256.f);
    float rinv = rsqrtf(s2 * (1.f/256.f) - mu*mu + 1e-5f);
    // H overwrites this wave's OWN Hbuf rows; own X' reads already consumed (R15-proven).
    #pragma unroll
    for (int ot = 0; ot < 16; ot++){
      int ob = ot*16 + quad*4;
      ushort4 hv;
      hv.x = f2b(fmaxf((acc[ot][0] - mu) * rinv * sG[ob+0] + sBe[ob+0], 0.f));
      hv.y = f2b(fmaxf((acc[ot][1] - mu) * rinv * sG[ob+1] + sBe[ob+1], 0.f));
      hv.z = f2b(fmaxf((acc[ot][2] - mu) * rinv * sG[ob+2] + sBe[ob+2], 0.f));
      hv.w = f2b(fmaxf((acc[ot][3] - mu) * rinv * sG[ob+3] + sBe[ob+3], 0.f));
      *(ushort4*)(Hbuf + ml*264 + ot*16 + quad*4) = hv;
    }
  }

  // ---------------- phase 2: out = relu(LN2(W2 @ H + b2)) — 4 chunks of K=64 ----------------
  #pragma unroll
  for (int i = 0; i < 16; i++) acc[i] = (f32x4)0.0f;
  for (int c = 0; c < 4; c++){
    bar_sync();        // c=0: all waves past epilogue-1 (program order) -> sB swap safe below
    {
      int4* d4 = (int4*)(Ws + tid * 72);
      #pragma unroll
      for (int i = 0; i < 8; i++) d4[i] = wB[i];
    }
    if (c == 0){ sB[tid] = rb2; sG[tid] = rg2; sBe[tid] = rbe2; }
    if (c + 1 < 4){
      #pragma unroll
      for (int i = 0; i < 8; i++) wB[i] = w2src[(c+1)*8 + i];
    }
    bar_sync();        // Ws (and c=0: param) writes visible
    #pragma unroll
    for (int ks = 0; ks < 2; ks++){
      bf16x8 bfrag = *(const bf16x8*)(Hbuf + ml*264 + (c*2+ks)*32 + quad*8);   // own row
      #pragma unroll
      for (int ot = 0; ot < 16; ot++){
        bf16x8 afrag = *(const bf16x8*)(Ws + (ot*16 + col)*72 + ks*32 + quad*8);
        acc[ot] = __builtin_amdgcn_mfma_f32_16x16x32_bf16(afrag, bfrag, acc[ot], 0, 0, 0);
      }
    }
  }
  float s1 = 0.f, s2 = 0.f;
  #pragma unroll
  for (int ot = 0; ot < 16; ot++)
    #pragma unroll
    for (int r = 0; r < 4; r++){
      int o = ot*16 + quad*4 + r;
      float v = acc[ot][r] + sB[o];
      acc[ot][r] = v;
      s1 += v; s2 += v*v;
    }
  s1 += __shfl_xor(s1, 16); s1 += __shfl_xor(s1, 32);
  s2 += __shfl_xor(s2, 16); s2 += __shfl_xor(s2, 32);
  float mu = s1 * (1.f/256.f);
  float rinv = rsqrtf(s2 * (1.f/256.f) - mu*mu + 1e-5f);
  size_t obase = (size_t)b * HD * NPT + n0 + w*16 + col;
  #pragma unroll
  for (int ot = 0; ot < 16; ot++)
    #pragma unroll
    for (int r = 0; r < 4; r++){
      int o = ot*16 + quad*4 + r;
      float v = (acc[ot][r] - mu) * rinv * sG[o] + sBe[o];
      outg[obase + (size_t)o * NPT] = fmaxf(v, 0.f);
    }
}

extern "C" void kernel_launch(void* const* d_in, const int* in_sizes, int n_in,
                              void* d_out, int out_size, void* d_ws, size_t ws_size,
                              hipStream_t stream){
  const float* coor1 = (const float*)d_in[0];
  const float* coor2 = (const float*)d_in[1];
  const float* fea1  = (const float*)d_in[2];
  const float* fea2  = (const float*)d_in[3];
  const unsigned char* pad = (const unsigned char*)d_in[4];
  const float* W1  = (const float*)d_in[5];
  const float* b1  = (const float*)d_in[6];
  const float* g1  = (const float*)d_in[7];
  const float* be1 = (const float*)d_in[8];
  const float* W2  = (const float*)d_in[9];
  const float* b2  = (const float*)d_in[10];
  const float* g2  = (const float*)d_in[11];
  const float* be2 = (const float*)d_in[12];
  float* out = (float*)d_out;

  // ws layout (~94.2 MB, proven footprint): | W1b | W2b | f2t | xpm | scratch
  // cv/cj/gs alias the old Hg region (knn-stage scratch only)
  char* ws = (char*)d_ws;
  unsigned short* W1b  = (unsigned short*)(ws + 1573120);
  unsigned short* W2b  = (unsigned short*)(ws + 1769728);
  unsigned short* f2t  = (unsigned short*)(ws + 1900800);
  unsigned short* xpm  = (unsigned short*)(ws + 10289408);
  float* cv            = (float*)(ws + 60621056);             // knn scratch
  int*   cj            = (int*)  (ws + 60621056 + 6291456);
  float4* gs           = (float4*)(ws + 60621056 + 16777216);

  gsrc_kernel<<<BB*SPT/256, 256, 0, stream>>>(coor2, pad, gs);
  main_kernel<<<NB_KNN + NB_CVT + NB_T2 + NB_T1, 256, 0, stream>>>(
      coor1, gs, cv, cj, W1, W2, W1b, fea2, f2t, fea1, xpm);
  mlp_fused_kernel<<<BB*NPT/64, 256, 0, stream>>>(
      cv, cj, f2t, xpm, W1b, W2b, b1, g1, be1, b2, g2, be2, out);
}